// Round 16
// baseline (86.287 us; speedup 1.0000x reference)
//
#include <hip/hip_runtime.h>
#include <hip/hip_bf16.h>
#include <stdint.h>

#define NN 50000
#define NE 800000
#define DD 128
#define NBKT 3125        // 50000/16 dst buckets of 16 nodes (exact)
#define BCH 4096         // edges per workgroup in bscat
#define BGRID ((NE + BCH - 1) / BCH)   // 196
#define CAP 384          // per-bucket slab capacity (mean 256, sigma ~16, +8 sigma)
#define SPILL_CAP 32768
#define GROWS 64         // gemm rows per block
#define GGRID ((NN + GROWS - 1) / GROWS)  // 782

typedef __attribute__((ext_vector_type(8))) unsigned short ushort8;
typedef __attribute__((ext_vector_type(8))) short short8;
typedef __attribute__((ext_vector_type(4))) float f32x4;

__device__ inline uint32_t cvtpk(float lo, float hi) {   // bf16(lo) in [15:0], bf16(hi) in [31:16], RNE
    uint32_t r;
    asm("v_cvt_pk_bf16_f32 %0, %1, %2" : "=v"(r) : "v"(lo), "v"(hi));
    return r;
}
__device__ inline float bf_lo(uint32_t u) { return __uint_as_float(u << 16); }
__device__ inline float bf_hi(uint32_t u) { return __uint_as_float(u & 0xffff0000u); }

// ---------- prep: W f32 -> bf16 + zero bucket counters ----------
__global__ __launch_bounds__(256) void prep_k(const float* __restrict__ W,
                                              uint16_t* __restrict__ Wb,
                                              int* __restrict__ cntg) {
    int t = threadIdx.x;
    if (blockIdx.x < 13) {
        for (int k = blockIdx.x * 256 + t; k < NBKT + 4; k += 13 * 256) cntg[k] = 0;
    }
    int i = blockIdx.x * 256 + t;
    if (i < DD * DD) {
        uint32_t u = __float_as_uint(W[i]);
        Wb[i] = (uint16_t)((u + 0x7fffu + ((u >> 16) & 1u)) >> 16);
    }
}

// ---------- fused: gemm (blocks < GGRID) || bscat (blocks >= GGRID) ----------
// gemm: block = 64 rows x 128 cols, 4 waves, NO LDS. Wave wid: rows r0+wid*16..+16, all cols.
// h stored PERMUTED: ushort position p = lr*8+c holds col c*16+lr.
__global__ __launch_bounds__(256) void fused_k(const float* __restrict__ x,
                                               const uint16_t* __restrict__ Wb,
                                               const float* __restrict__ a,
                                               const int* __restrict__ src,
                                               const int* __restrict__ dst,
                                               uint16_t* __restrict__ hb,
                                               float* __restrict__ sArr,
                                               float* __restrict__ dArr,
                                               int* __restrict__ cntg,
                                               int* __restrict__ scnt,
                                               uint32_t* __restrict__ rec,
                                               uint2* __restrict__ spill) {
    __shared__ int lh[NBKT];
    __shared__ int gb[NBKT];
    const int t = threadIdx.x;

    if ((int)blockIdx.x < GGRID) {
        // ---------------- GEMM role ----------------
        const int l = t & 63, wid = t >> 6;
        const int r0 = blockIdx.x * GROWS;
        const int lr = l & 15, lk = l >> 4;

        f32x4 acc[8];
        #pragma unroll
        for (int c = 0; c < 8; ++c) acc[c] = f32x4{0.f, 0.f, 0.f, 0.f};

        const int arow = r0 + wid * 16 + lr;
        const int lrow = (arow < NN) ? arow : (NN - 1);        // clamp loads; guard stores
        const float* xp = x + (size_t)lrow * DD + lk * 8;

        #pragma unroll
        for (int kc = 0; kc < 4; ++kc) {
            float4 v0 = *(const float4*)(xp + kc * 32);
            float4 v1 = *(const float4*)(xp + kc * 32 + 4);
            union { uint32_t u[4]; short8 s; } A;
            A.u[0] = cvtpk(v0.x, v0.y); A.u[1] = cvtpk(v0.z, v0.w);
            A.u[2] = cvtpk(v1.x, v1.y); A.u[3] = cvtpk(v1.z, v1.w);
            #pragma unroll
            for (int c = 0; c < 8; ++c) {
                int col = c * 16 + lr;
                short8 bf_ = *(const short8*)(Wb + (size_t)col * DD + kc * 32 + lk * 8);
                acc[c] = __builtin_amdgcn_mfma_f32_16x16x32_bf16(A.s, bf_, acc[c], 0, 0, 0);
            }
        }

        // s/d projections (wave-local shuffle reduce over the 16 lr lanes)
        float avs[8], avd[8];
        #pragma unroll
        for (int c = 0; c < 8; ++c) {
            avs[c] = a[c * 16 + lr];
            avd[c] = a[DD + c * 16 + lr];
        }
        #pragma unroll
        for (int i = 0; i < 4; ++i) {
            float ps = 0.f, pd = 0.f;
            #pragma unroll
            for (int c = 0; c < 8; ++c) {
                ps = fmaf(acc[c][i], avs[c], ps);
                pd = fmaf(acc[c][i], avd[c], pd);
            }
            #pragma unroll
            for (int o = 8; o > 0; o >>= 1) {
                ps += __shfl_xor(ps, o);
                pd += __shfl_xor(pd, o);
            }
            int row = r0 + wid * 16 + lk * 4 + i;
            if (lr == 0 && row < NN) { sArr[row] = ps; dArr[row] = pd; }
        }

        // permuted h writeback: 4 x ushort8 per lane, no LDS
        #pragma unroll
        for (int i = 0; i < 4; ++i) {
            int row = r0 + wid * 16 + lk * 4 + i;
            if (row < NN) {
                union { uint32_t u[4]; ushort8 s; } H;
                H.u[0] = cvtpk(acc[0][i], acc[1][i]);
                H.u[1] = cvtpk(acc[2][i], acc[3][i]);
                H.u[2] = cvtpk(acc[4][i], acc[5][i]);
                H.u[3] = cvtpk(acc[6][i], acc[7][i]);
                *(ushort8*)(hb + (size_t)row * DD + lr * 8) = H.s;
            }
        }
    } else {
        // ---------------- BSCAT role ----------------
        int bb = blockIdx.x - GGRID;
        for (int k = t; k < NBKT; k += 256) lh[k] = 0;
        __syncthreads();
        int base = bb * BCH;
        unsigned pk[16]; int bk[16];
        #pragma unroll
        for (int i = 0; i < 16; ++i) {
            int idx = base + i * 256 + t;
            if (idx < NE) {
                int s_ = src[idx], d_ = dst[idx];
                bk[i] = d_ >> 4;
                pk[i] = ((unsigned)(d_ & 15) << 16) | (unsigned)s_;
                atomicAdd(&lh[bk[i]], 1);
            } else bk[i] = -1;
        }
        __syncthreads();
        for (int k = t; k < NBKT; k += 256) {
            int c = lh[k];
            lh[k] = 0;                       // becomes local cursor
            gb[k] = c ? atomicAdd(&cntg[k], c) : 0;
        }
        __syncthreads();
        #pragma unroll
        for (int i = 0; i < 16; ++i) {
            if (bk[i] >= 0) {
                int sl = atomicAdd(&lh[bk[i]], 1);
                int p = gb[bk[i]] + sl;
                if (p < CAP) {
                    rec[(size_t)bk[i] * CAP + p] = pk[i];
                } else {
                    int sp = atomicAdd(scnt, 1);
                    if (sp < SPILL_CAP)
                        spill[sp] = make_uint2(pk[i] & 0xffffu,
                                               (unsigned)(bk[i] * 16 + (int)(pk[i] >> 16)));
                }
            }
        }
    }
}

// ---------- agg: WG per 16-node bucket; node sort; 4 column-passes (3.2MB L2-resident slice) ----------
// quarter q owns node d = wid*4+q. Within a pass, its 16 lanes serve 4 edges x 16B each.
__global__ __launch_bounds__(256) void bsort_agg_k(const uint16_t* __restrict__ hb,
                                                   const float* __restrict__ sA,
                                                   const float* __restrict__ dA,
                                                   const int* __restrict__ cntg,
                                                   const uint32_t* __restrict__ rec,
                                                   const int* __restrict__ scnt,
                                                   const uint2* __restrict__ spill,
                                                   float* __restrict__ out) {
    __shared__ uint32_t srt[CAP];   // 1.5 KB
    __shared__ float    eL[CAP];    // 1.5 KB
    __shared__ float dAl[16];
    __shared__ int h16[16];
    __shared__ int s17[17];
    __shared__ int curw[16];
    int t = threadIdx.x, l = t & 63, wid = t >> 6;
    int b = blockIdx.x;
    int cnt = cntg[b]; if (cnt > CAP) cnt = CAP;
    int beg = b * CAP;
    int n0 = b * 16;
    int ns = *scnt; if (ns > SPILL_CAP) ns = SPILL_CAP;
    if (t < 16) { h16[t] = 0; dAl[t] = dA[n0 + t]; }
    __syncthreads();

    // histogram + fused e-compute (records cached in registers; <=2 per thread)
    uint32_t rc[2]; float er[2]; int nrc = 0;
    for (int j = t; j < cnt; j += 256) {
        uint32_t r = rec[beg + j];
        rc[nrc] = r;
        atomicAdd(&h16[r >> 16], 1);
        float z = sA[r & 0xffffu] + dAl[r >> 16];
        er[nrc] = 1.f / (1.f + __expf(-z));
        ++nrc;
    }
    __syncthreads();
    if (wid == 0) {
        int v = (l < 16) ? h16[l] : 0;
        int inc = v;
        #pragma unroll
        for (int o = 1; o < 16; o <<= 1) {
            int nb = __shfl_up(inc, o);
            if (l >= o) inc += nb;
        }
        if (l < 16) { s17[l + 1] = inc; curw[l] = inc - v; }
        if (l == 0) s17[0] = 0;
    }
    __syncthreads();
    for (int k = 0; k < nrc; ++k) {
        uint32_t r = rc[k];
        int p = atomicAdd(&curw[r >> 16], 1);
        srt[p] = r;
        eL[p] = er[k];
    }
    __syncthreads();

    // 4 column-passes. Pass p touches only bytes [p*64, p*64+64) of each h row:
    // per-pass footprint = 3.2 MB -> L2-resident on every XCD (all WGs sweep same order).
    // Lane sl = (ep=sl>>2, bg=sl&3): serves edge j+ep (and j+4+ep), 16B at byte bg*16.
    // ushort idx p*32+bg*8+k -> col = k*16 + (p*4+bg).
    const int q = l >> 4, sl = l & 15;
    const int ep = sl >> 2;
    const int bo = (sl & 3) * 16;
    const int d = wid * 4 + q;          // this quarter's node (0..15)
    const int n = n0 + d;
    const char* hbp = (const char*)hb;
    const int js = s17[d], je = s17[d + 1];
    float acc[4][8];
    #pragma unroll
    for (int p = 0; p < 4; ++p)
        #pragma unroll
        for (int k = 0; k < 8; ++k) acc[p][k] = 0.f;

    #pragma unroll
    for (int p = 0; p < 4; ++p) {
        const size_t po = (size_t)(p * 64 + bo);
        for (int j = js; j < je; j += 8) {
            int j0 = j + ep, j1 = j + 4 + ep;
            bool v0 = j0 < je, v1 = j1 < je;
            uint32_t r0 = srt[v0 ? j0 : js];
            uint32_t r1 = srt[v1 ? j1 : js];
            float e0 = v0 ? eL[j0] : 0.f;
            float e1 = v1 ? eL[j1] : 0.f;
            uint4 u0 = *(const uint4*)(hbp + (size_t)(r0 & 0xffffu) * 256 + po);
            uint4 u1 = *(const uint4*)(hbp + (size_t)(r1 & 0xffffu) * 256 + po);
            acc[p][0] = fmaf(e0, bf_lo(u0.x), acc[p][0]); acc[p][1] = fmaf(e0, bf_hi(u0.x), acc[p][1]);
            acc[p][2] = fmaf(e0, bf_lo(u0.y), acc[p][2]); acc[p][3] = fmaf(e0, bf_hi(u0.y), acc[p][3]);
            acc[p][4] = fmaf(e0, bf_lo(u0.z), acc[p][4]); acc[p][5] = fmaf(e0, bf_hi(u0.z), acc[p][5]);
            acc[p][6] = fmaf(e0, bf_lo(u0.w), acc[p][6]); acc[p][7] = fmaf(e0, bf_hi(u0.w), acc[p][7]);
            acc[p][0] = fmaf(e1, bf_lo(u1.x), acc[p][0]); acc[p][1] = fmaf(e1, bf_hi(u1.x), acc[p][1]);
            acc[p][2] = fmaf(e1, bf_lo(u1.y), acc[p][2]); acc[p][3] = fmaf(e1, bf_hi(u1.y), acc[p][3]);
            acc[p][4] = fmaf(e1, bf_lo(u1.z), acc[p][4]); acc[p][5] = fmaf(e1, bf_hi(u1.z), acc[p][5]);
            acc[p][6] = fmaf(e1, bf_lo(u1.w), acc[p][6]); acc[p][7] = fmaf(e1, bf_hi(u1.w), acc[p][7]);
        }
    }

    // fold edge-parity partials (lanes differing in bits 2-3 of sl hold the SAME cols)
    #pragma unroll
    for (int p = 0; p < 4; ++p)
        #pragma unroll
        for (int k = 0; k < 8; ++k) {
            acc[p][k] += __shfl_xor(acc[p][k], 4);
            acc[p][k] += __shfl_xor(acc[p][k], 8);
        }
    // lane sl takes pass (sl>>2): its cols are k*16 + (sl>>2)*4 + (sl&3) = k*16 + sl
    float v[8];
    #pragma unroll
    for (int k = 0; k < 8; ++k)
        v[k] = (ep == 0) ? acc[0][k] : (ep == 1) ? acc[1][k] : (ep == 2) ? acc[2][k] : acc[3][k];

    // inline spill drain (statistically near-empty); full-row read, col = k*16 + sl
    if (ns > 0) {
        for (int i = 0; i < ns; ++i) {
            uint2 sp = spill[i];
            if ((int)sp.y == n) {
                float z = sA[sp.x] + dAl[d];
                float e = 1.f / (1.f + __expf(-z));
                uint4 u = *(const uint4*)(hbp + (size_t)sp.x * 256 + sl * 16);
                v[0] = fmaf(e, bf_lo(u.x), v[0]); v[1] = fmaf(e, bf_hi(u.x), v[1]);
                v[2] = fmaf(e, bf_lo(u.y), v[2]); v[3] = fmaf(e, bf_hi(u.y), v[3]);
                v[4] = fmaf(e, bf_lo(u.z), v[4]); v[5] = fmaf(e, bf_hi(u.z), v[5]);
                v[6] = fmaf(e, bf_lo(u.w), v[6]); v[7] = fmaf(e, bf_hi(u.w), v[7]);
            }
        }
    }

    // store: quarter q's 16 lanes write node n's full row (cols k*16+sl)
    float* orow = out + (size_t)n * DD;
    #pragma unroll
    for (int k = 0; k < 8; ++k) orow[k * 16 + sl] = v[k];
}

// ---------- fallback: direct atomic scatter-add (permuted hb layout) ----------
__global__ __launch_bounds__(256) void edge_atomic_k(const int* __restrict__ src, const int* __restrict__ dst,
                                                     const float* __restrict__ sArr, const float* __restrict__ dArr,
                                                     const uint32_t* __restrict__ hb, float* __restrict__ out) {
    int wid = threadIdx.x >> 6, l = threadIdx.x & 63;
    int e = blockIdx.x * 4 + wid;
    if (e >= NE) return;
    int sv = src[e], dv = dst[e];
    float z = sArr[sv] + dArr[dv];
    float ev = 1.0f / (1.0f + __expf(-z));
    uint32_t u = hb[(size_t)sv * 64 + l];
    int colx = 32 * (l & 3) + (l >> 2);
    atomicAdd(&out[(size_t)dv * DD + colx],      ev * bf_lo(u));
    atomicAdd(&out[(size_t)dv * DD + colx + 16], ev * bf_hi(u));
}

extern "C" void kernel_launch(void* const* d_in, const int* in_sizes, int n_in,
                              void* d_out, int out_size, void* d_ws, size_t ws_size,
                              hipStream_t stream) {
    const float* x  = (const float*)d_in[0];
    const float* W  = (const float*)d_in[1];
    const float* a  = (const float*)d_in[2];
    const int* src  = (const int*)d_in[3];
    const int* dst  = (const int*)d_in[4];
    float* out = (float*)d_out;

    char* p = (char*)d_ws;
    uint16_t* hb = (uint16_t*)p;            p += (size_t)NN * DD * 2;       // 12.8 MB
    uint16_t* Wb = (uint16_t*)p;            p += (size_t)DD * DD * 2;       // 32 KB
    float* sA    = (float*)p;               p += (size_t)NN * 4;
    float* dA    = (float*)p;               p += (size_t)NN * 4;
    int*   cntg  = (int*)p;                 p += (size_t)NBKT * 4;
    int*   scnt  = (int*)p;                 p += 16;
    uint32_t* rec = (uint32_t*)(((uintptr_t)p + 15) & ~(uintptr_t)15);
    p = (char*)(rec + (size_t)NBKT * CAP);                                   // 4.8 MB
    uint2* spill = (uint2*)p;               p += (size_t)SPILL_CAP * 8;      // 0.25 MB
    size_t need  = (size_t)(p - (char*)d_ws);

    if (ws_size >= need) {
        prep_k<<<64, 256, 0, stream>>>(W, Wb, cntg);                 // zeros cntg+scnt
        fused_k<<<GGRID + BGRID, 256, 0, stream>>>(x, Wb, a, src, dst,
                                                   hb, sA, dA, cntg, scnt, rec, spill);
        bsort_agg_k<<<NBKT, 256, 0, stream>>>(hb, sA, dA, cntg, rec, scnt, spill, out);
    } else {
        hipMemsetAsync(out, 0, sizeof(float) * (size_t)NN * DD, stream);
        prep_k<<<64, 256, 0, stream>>>(W, Wb, cntg);
        fused_k<<<GGRID, 256, 0, stream>>>(x, Wb, a, src, dst,
                                           hb, sA, dA, cntg, scnt, rec, spill);
        edge_atomic_k<<<NE / 4, 256, 0, stream>>>(src, dst, sA, dA, (const uint32_t*)hb, out);
    }
}

// Round 17
// 74.105 us; speedup vs baseline: 1.1644x; 1.1644x over previous
//
#include <hip/hip_runtime.h>
#include <hip/hip_bf16.h>
#include <stdint.h>

#define NN 50000
#define NE 800000
#define DD 128
#define NBKT 3125        // 50000/16 dst buckets of 16 nodes (exact)
#define BCH 4096         // edges per workgroup in bscat
#define BGRID ((NE + BCH - 1) / BCH)   // 196
#define CAP 384          // per-bucket slab capacity (mean 256, sigma ~16, +8 sigma)
#define SPILL_CAP 32768
#define GROWS 64         // gemm rows per block
#define GGRID ((NN + GROWS - 1) / GROWS)  // 782

typedef __attribute__((ext_vector_type(8))) unsigned short ushort8;
typedef __attribute__((ext_vector_type(8))) short short8;
typedef __attribute__((ext_vector_type(4))) float f32x4;

__device__ inline uint32_t cvtpk(float lo, float hi) {   // bf16(lo) in [15:0], bf16(hi) in [31:16], RNE
    uint32_t r;
    asm("v_cvt_pk_bf16_f32 %0, %1, %2" : "=v"(r) : "v"(lo), "v"(hi));
    return r;
}
__device__ inline float bf_lo(uint32_t u) { return __uint_as_float(u << 16); }
__device__ inline float bf_hi(uint32_t u) { return __uint_as_float(u & 0xffff0000u); }

// ---------- prep: W f32 -> bf16 + zero bucket counters ----------
__global__ __launch_bounds__(256) void prep_k(const float* __restrict__ W,
                                              uint16_t* __restrict__ Wb,
                                              int* __restrict__ cntg) {
    int t = threadIdx.x;
    if (blockIdx.x < 13) {
        for (int k = blockIdx.x * 256 + t; k < NBKT + 4; k += 13 * 256) cntg[k] = 0;
    }
    int i = blockIdx.x * 256 + t;
    if (i < DD * DD) {
        uint32_t u = __float_as_uint(W[i]);
        Wb[i] = (uint16_t)((u + 0x7fffu + ((u >> 16) & 1u)) >> 16);
    }
}

// ---------- fused: gemm (blocks < GGRID) || bscat (blocks >= GGRID) ----------
// gemm: block = 64 rows x 128 cols, 4 waves, NO LDS. Wave wid: rows r0+wid*16..+16, all cols.
// h stored PERMUTED: ushort position p = lr*8+c holds col c*16+lr.
__global__ __launch_bounds__(256) void fused_k(const float* __restrict__ x,
                                               const uint16_t* __restrict__ Wb,
                                               const float* __restrict__ a,
                                               const int* __restrict__ src,
                                               const int* __restrict__ dst,
                                               uint16_t* __restrict__ hb,
                                               float* __restrict__ sArr,
                                               float* __restrict__ dArr,
                                               int* __restrict__ cntg,
                                               int* __restrict__ scnt,
                                               uint32_t* __restrict__ rec,
                                               uint2* __restrict__ spill) {
    __shared__ int lh[NBKT];
    __shared__ int gb[NBKT];
    const int t = threadIdx.x;

    if ((int)blockIdx.x < GGRID) {
        // ---------------- GEMM role ----------------
        const int l = t & 63, wid = t >> 6;
        const int r0 = blockIdx.x * GROWS;
        const int lr = l & 15, lk = l >> 4;

        f32x4 acc[8];
        #pragma unroll
        for (int c = 0; c < 8; ++c) acc[c] = f32x4{0.f, 0.f, 0.f, 0.f};

        const int arow = r0 + wid * 16 + lr;
        const int lrow = (arow < NN) ? arow : (NN - 1);        // clamp loads; guard stores
        const float* xp = x + (size_t)lrow * DD + lk * 8;

        #pragma unroll
        for (int kc = 0; kc < 4; ++kc) {
            float4 v0 = *(const float4*)(xp + kc * 32);
            float4 v1 = *(const float4*)(xp + kc * 32 + 4);
            union { uint32_t u[4]; short8 s; } A;
            A.u[0] = cvtpk(v0.x, v0.y); A.u[1] = cvtpk(v0.z, v0.w);
            A.u[2] = cvtpk(v1.x, v1.y); A.u[3] = cvtpk(v1.z, v1.w);
            #pragma unroll
            for (int c = 0; c < 8; ++c) {
                int col = c * 16 + lr;
                short8 bf_ = *(const short8*)(Wb + (size_t)col * DD + kc * 32 + lk * 8);
                acc[c] = __builtin_amdgcn_mfma_f32_16x16x32_bf16(A.s, bf_, acc[c], 0, 0, 0);
            }
        }

        // s/d projections (wave-local shuffle reduce over the 16 lr lanes)
        float avs[8], avd[8];
        #pragma unroll
        for (int c = 0; c < 8; ++c) {
            avs[c] = a[c * 16 + lr];
            avd[c] = a[DD + c * 16 + lr];
        }
        #pragma unroll
        for (int i = 0; i < 4; ++i) {
            float ps = 0.f, pd = 0.f;
            #pragma unroll
            for (int c = 0; c < 8; ++c) {
                ps = fmaf(acc[c][i], avs[c], ps);
                pd = fmaf(acc[c][i], avd[c], pd);
            }
            #pragma unroll
            for (int o = 8; o > 0; o >>= 1) {
                ps += __shfl_xor(ps, o);
                pd += __shfl_xor(pd, o);
            }
            int row = r0 + wid * 16 + lk * 4 + i;
            if (lr == 0 && row < NN) { sArr[row] = ps; dArr[row] = pd; }
        }

        // permuted h writeback: 4 x ushort8 per lane, no LDS
        #pragma unroll
        for (int i = 0; i < 4; ++i) {
            int row = r0 + wid * 16 + lk * 4 + i;
            if (row < NN) {
                union { uint32_t u[4]; ushort8 s; } H;
                H.u[0] = cvtpk(acc[0][i], acc[1][i]);
                H.u[1] = cvtpk(acc[2][i], acc[3][i]);
                H.u[2] = cvtpk(acc[4][i], acc[5][i]);
                H.u[3] = cvtpk(acc[6][i], acc[7][i]);
                *(ushort8*)(hb + (size_t)row * DD + lr * 8) = H.s;
            }
        }
    } else {
        // ---------------- BSCAT role ----------------
        int bb = blockIdx.x - GGRID;
        for (int k = t; k < NBKT; k += 256) lh[k] = 0;
        __syncthreads();
        int base = bb * BCH;
        unsigned pk[16]; int bk[16];
        #pragma unroll
        for (int i = 0; i < 16; ++i) {
            int idx = base + i * 256 + t;
            if (idx < NE) {
                int s_ = src[idx], d_ = dst[idx];
                bk[i] = d_ >> 4;
                pk[i] = ((unsigned)(d_ & 15) << 16) | (unsigned)s_;
                atomicAdd(&lh[bk[i]], 1);
            } else bk[i] = -1;
        }
        __syncthreads();
        for (int k = t; k < NBKT; k += 256) {
            int c = lh[k];
            lh[k] = 0;                       // becomes local cursor
            gb[k] = c ? atomicAdd(&cntg[k], c) : 0;
        }
        __syncthreads();
        #pragma unroll
        for (int i = 0; i < 16; ++i) {
            if (bk[i] >= 0) {
                int sl = atomicAdd(&lh[bk[i]], 1);
                int p = gb[bk[i]] + sl;
                if (p < CAP) {
                    rec[(size_t)bk[i] * CAP + p] = pk[i];
                } else {
                    int sp = atomicAdd(scnt, 1);
                    if (sp < SPILL_CAP)
                        spill[sp] = make_uint2(pk[i] & 0xffffu,
                                               (unsigned)(bk[i] * 16 + (int)(pk[i] >> 16)));
                }
            }
        }
    }
}

// ---------- agg: WG per 16-node bucket; node sort; two-stream ILP-4 gather ----------
// quarter q owns node d = wid*4+q; its 16 lanes read the full 256B row of each record.
__global__ __launch_bounds__(256) void bsort_agg_k(const uint16_t* __restrict__ hb,
                                                   const float* __restrict__ sA,
                                                   const float* __restrict__ dA,
                                                   const int* __restrict__ cntg,
                                                   const uint32_t* __restrict__ rec,
                                                   const int* __restrict__ scnt,
                                                   const uint2* __restrict__ spill,
                                                   float* __restrict__ out) {
    __shared__ uint32_t srt[CAP];   // 1.5 KB
    __shared__ float    eL[CAP];    // 1.5 KB
    __shared__ float dAl[16];
    __shared__ int h16[16];
    __shared__ int s17[17];
    __shared__ int curw[16];
    int t = threadIdx.x, l = t & 63, wid = t >> 6;
    int b = blockIdx.x;
    int cnt = cntg[b]; if (cnt > CAP) cnt = CAP;
    int beg = b * CAP;
    int n0 = b * 16;
    int ns = *scnt; if (ns > SPILL_CAP) ns = SPILL_CAP;
    if (t < 16) { h16[t] = 0; dAl[t] = dA[n0 + t]; }
    __syncthreads();

    // histogram + fused e-compute (records cached in registers; <=2 per thread)
    uint32_t rc[2]; float er[2]; int nrc = 0;
    for (int j = t; j < cnt; j += 256) {
        uint32_t r = rec[beg + j];
        rc[nrc] = r;
        atomicAdd(&h16[r >> 16], 1);
        float z = sA[r & 0xffffu] + dAl[r >> 16];
        er[nrc] = 1.f / (1.f + __expf(-z));
        ++nrc;
    }
    __syncthreads();
    if (wid == 0) {
        int v = (l < 16) ? h16[l] : 0;
        int inc = v;
        #pragma unroll
        for (int o = 1; o < 16; o <<= 1) {
            int nb = __shfl_up(inc, o);
            if (l >= o) inc += nb;
        }
        if (l < 16) { s17[l + 1] = inc; curw[l] = inc - v; }
        if (l == 0) s17[0] = 0;
    }
    __syncthreads();
    for (int k = 0; k < nrc; ++k) {
        uint32_t r = rc[k];
        int p = atomicAdd(&curw[r >> 16], 1);
        srt[p] = r;
        eL[p] = er[k];
    }
    __syncthreads();

    // two-stream gather: stream A = [js, jm), stream B = [jm, jm+ht); main loop is
    // fully unguarded (ht = jm-js even, 2*ht <= len), 4 independent dwordx4 in flight.
    const int q = l >> 4, sl = l & 15;
    const int d = wid * 4 + q;          // this quarter's node (0..15)
    const int n = n0 + d;
    const char* hbp = (const char*)hb;
    const int js = s17[d], je = s17[d + 1];
    const int len = je - js;
    const int ht = (len >> 1) & ~1;     // even half
    const int jm = js + ht;
    float a0[8] = {0.f,0.f,0.f,0.f,0.f,0.f,0.f,0.f};
    float a1[8] = {0.f,0.f,0.f,0.f,0.f,0.f,0.f,0.f};

    int ja = js, jb = jm;
    for (; ja < jm; ja += 2, jb += 2) {
        uint32_t rA0 = srt[ja], rA1 = srt[ja + 1];
        uint32_t rB0 = srt[jb], rB1 = srt[jb + 1];
        float eA0 = eL[ja], eA1 = eL[ja + 1];
        float eB0 = eL[jb], eB1 = eL[jb + 1];
        uint4 uA0 = *(const uint4*)(hbp + (size_t)(rA0 & 0xffffu) * 256 + sl * 16);
        uint4 uA1 = *(const uint4*)(hbp + (size_t)(rA1 & 0xffffu) * 256 + sl * 16);
        uint4 uB0 = *(const uint4*)(hbp + (size_t)(rB0 & 0xffffu) * 256 + sl * 16);
        uint4 uB1 = *(const uint4*)(hbp + (size_t)(rB1 & 0xffffu) * 256 + sl * 16);
        a0[0] = fmaf(eA0, bf_lo(uA0.x), a0[0]); a0[1] = fmaf(eA0, bf_hi(uA0.x), a0[1]);
        a0[2] = fmaf(eA0, bf_lo(uA0.y), a0[2]); a0[3] = fmaf(eA0, bf_hi(uA0.y), a0[3]);
        a0[4] = fmaf(eA0, bf_lo(uA0.z), a0[4]); a0[5] = fmaf(eA0, bf_hi(uA0.z), a0[5]);
        a0[6] = fmaf(eA0, bf_lo(uA0.w), a0[6]); a0[7] = fmaf(eA0, bf_hi(uA0.w), a0[7]);
        a1[0] = fmaf(eA1, bf_lo(uA1.x), a1[0]); a1[1] = fmaf(eA1, bf_hi(uA1.x), a1[1]);
        a1[2] = fmaf(eA1, bf_lo(uA1.y), a1[2]); a1[3] = fmaf(eA1, bf_hi(uA1.y), a1[3]);
        a1[4] = fmaf(eA1, bf_lo(uA1.z), a1[4]); a1[5] = fmaf(eA1, bf_hi(uA1.z), a1[5]);
        a1[6] = fmaf(eA1, bf_lo(uA1.w), a1[6]); a1[7] = fmaf(eA1, bf_hi(uA1.w), a1[7]);
        a0[0] = fmaf(eB0, bf_lo(uB0.x), a0[0]); a0[1] = fmaf(eB0, bf_hi(uB0.x), a0[1]);
        a0[2] = fmaf(eB0, bf_lo(uB0.y), a0[2]); a0[3] = fmaf(eB0, bf_hi(uB0.y), a0[3]);
        a0[4] = fmaf(eB0, bf_lo(uB0.z), a0[4]); a0[5] = fmaf(eB0, bf_hi(uB0.z), a0[5]);
        a0[6] = fmaf(eB0, bf_lo(uB0.w), a0[6]); a0[7] = fmaf(eB0, bf_hi(uB0.w), a0[7]);
        a1[0] = fmaf(eB1, bf_lo(uB1.x), a1[0]); a1[1] = fmaf(eB1, bf_hi(uB1.x), a1[1]);
        a1[2] = fmaf(eB1, bf_lo(uB1.y), a1[2]); a1[3] = fmaf(eB1, bf_hi(uB1.y), a1[3]);
        a1[4] = fmaf(eB1, bf_lo(uB1.z), a1[4]); a1[5] = fmaf(eB1, bf_hi(uB1.z), a1[5]);
        a1[6] = fmaf(eB1, bf_lo(uB1.w), a1[6]); a1[7] = fmaf(eB1, bf_hi(uB1.w), a1[7]);
    }
    // tail: [jm+ht, je), at most 3 records
    for (int j = jm + ht; j < je; ++j) {
        uint32_t r = srt[j];
        float e = eL[j];
        uint4 u = *(const uint4*)(hbp + (size_t)(r & 0xffffu) * 256 + sl * 16);
        a0[0] = fmaf(e, bf_lo(u.x), a0[0]); a0[1] = fmaf(e, bf_hi(u.x), a0[1]);
        a0[2] = fmaf(e, bf_lo(u.y), a0[2]); a0[3] = fmaf(e, bf_hi(u.y), a0[3]);
        a0[4] = fmaf(e, bf_lo(u.z), a0[4]); a0[5] = fmaf(e, bf_hi(u.z), a0[5]);
        a0[6] = fmaf(e, bf_lo(u.w), a0[6]); a0[7] = fmaf(e, bf_hi(u.w), a0[7]);
    }
    float v[8];
    #pragma unroll
    for (int k = 0; k < 8; ++k) v[k] = a0[k] + a1[k];

    // inline spill drain (statistically near-empty); full-row read, col = k*16 + sl
    if (ns > 0) {
        for (int i = 0; i < ns; ++i) {
            uint2 sp = spill[i];
            if ((int)sp.y == n) {
                float z = sA[sp.x] + dAl[d];
                float e = 1.f / (1.f + __expf(-z));
                uint4 u = *(const uint4*)(hbp + (size_t)sp.x * 256 + sl * 16);
                v[0] = fmaf(e, bf_lo(u.x), v[0]); v[1] = fmaf(e, bf_hi(u.x), v[1]);
                v[2] = fmaf(e, bf_lo(u.y), v[2]); v[3] = fmaf(e, bf_hi(u.y), v[3]);
                v[4] = fmaf(e, bf_lo(u.z), v[4]); v[5] = fmaf(e, bf_hi(u.z), v[5]);
                v[6] = fmaf(e, bf_lo(u.w), v[6]); v[7] = fmaf(e, bf_hi(u.w), v[7]);
            }
        }
    }

    // store: quarter q's 16 lanes write node n's full row (cols k*16+sl)
    float* orow = out + (size_t)n * DD;
    #pragma unroll
    for (int k = 0; k < 8; ++k) orow[k * 16 + sl] = v[k];
}

// ---------- fallback: direct atomic scatter-add (permuted hb layout) ----------
__global__ __launch_bounds__(256) void edge_atomic_k(const int* __restrict__ src, const int* __restrict__ dst,
                                                     const float* __restrict__ sArr, const float* __restrict__ dArr,
                                                     const uint32_t* __restrict__ hb, float* __restrict__ out) {
    int wid = threadIdx.x >> 6, l = threadIdx.x & 63;
    int e = blockIdx.x * 4 + wid;
    if (e >= NE) return;
    int sv = src[e], dv = dst[e];
    float z = sArr[sv] + dArr[dv];
    float ev = 1.0f / (1.0f + __expf(-z));
    uint32_t u = hb[(size_t)sv * 64 + l];
    int colx = 32 * (l & 3) + (l >> 2);
    atomicAdd(&out[(size_t)dv * DD + colx],      ev * bf_lo(u));
    atomicAdd(&out[(size_t)dv * DD + colx + 16], ev * bf_hi(u));
}

extern "C" void kernel_launch(void* const* d_in, const int* in_sizes, int n_in,
                              void* d_out, int out_size, void* d_ws, size_t ws_size,
                              hipStream_t stream) {
    const float* x  = (const float*)d_in[0];
    const float* W  = (const float*)d_in[1];
    const float* a  = (const float*)d_in[2];
    const int* src  = (const int*)d_in[3];
    const int* dst  = (const int*)d_in[4];
    float* out = (float*)d_out;

    char* p = (char*)d_ws;
    uint16_t* hb = (uint16_t*)p;            p += (size_t)NN * DD * 2;       // 12.8 MB
    uint16_t* Wb = (uint16_t*)p;            p += (size_t)DD * DD * 2;       // 32 KB
    float* sA    = (float*)p;               p += (size_t)NN * 4;
    float* dA    = (float*)p;               p += (size_t)NN * 4;
    int*   cntg  = (int*)p;                 p += (size_t)NBKT * 4;
    int*   scnt  = (int*)p;                 p += 16;
    uint32_t* rec = (uint32_t*)(((uintptr_t)p + 15) & ~(uintptr_t)15);
    p = (char*)(rec + (size_t)NBKT * CAP);                                   // 4.8 MB
    uint2* spill = (uint2*)p;               p += (size_t)SPILL_CAP * 8;      // 0.25 MB
    size_t need  = (size_t)(p - (char*)d_ws);

    if (ws_size >= need) {
        prep_k<<<64, 256, 0, stream>>>(W, Wb, cntg);                 // zeros cntg+scnt
        fused_k<<<GGRID + BGRID, 256, 0, stream>>>(x, Wb, a, src, dst,
                                                   hb, sA, dA, cntg, scnt, rec, spill);
        bsort_agg_k<<<NBKT, 256, 0, stream>>>(hb, sA, dA, cntg, rec, scnt, spill, out);
    } else {
        hipMemsetAsync(out, 0, sizeof(float) * (size_t)NN * DD, stream);
        prep_k<<<64, 256, 0, stream>>>(W, Wb, cntg);
        fused_k<<<GGRID, 256, 0, stream>>>(x, Wb, a, src, dst,
                                           hb, sA, dA, cntg, scnt, rec, spill);
        edge_atomic_k<<<NE / 4, 256, 0, stream>>>(src, dst, sA, dA, (const uint32_t*)hb, out);
    }
}

// Round 18
// 71.250 us; speedup vs baseline: 1.2110x; 1.0401x over previous
//
#include <hip/hip_runtime.h>
#include <hip/hip_bf16.h>
#include <stdint.h>

#define NN 50000
#define NE 800000
#define DD 128
#define NBKT 1563        // ceil(NN/32) dst buckets of 32 nodes
#define BCH 4096         // edges per workgroup in bscat
#define BGRID ((NE + BCH - 1) / BCH)   // 196
#define CAP 640          // per-bucket slab capacity (mean 512, sigma ~23)
#define SPILL_CAP 32768
#define GROWS 64         // gemm rows per block
#define GGRID ((NN + GROWS - 1) / GROWS)  // 782

typedef __attribute__((ext_vector_type(8))) unsigned short ushort8;
typedef __attribute__((ext_vector_type(8))) short short8;
typedef __attribute__((ext_vector_type(4))) float f32x4;

__device__ inline uint32_t cvtpk(float lo, float hi) {   // bf16(lo) in [15:0], bf16(hi) in [31:16], RNE
    uint32_t r;
    asm("v_cvt_pk_bf16_f32 %0, %1, %2" : "=v"(r) : "v"(lo), "v"(hi));
    return r;
}
__device__ inline float bf_lo(uint32_t u) { return __uint_as_float(u << 16); }
__device__ inline float bf_hi(uint32_t u) { return __uint_as_float(u & 0xffff0000u); }

// ---------- prep: W f32 -> bf16 + zero bucket counters ----------
__global__ __launch_bounds__(256) void prep_k(const float* __restrict__ W,
                                              uint16_t* __restrict__ Wb,
                                              int* __restrict__ cntg) {
    int t = threadIdx.x;
    if (blockIdx.x == 0) {
        for (int k = t; k < NBKT + 4; k += 256) cntg[k] = 0;   // cntg + scnt
    }
    int i = blockIdx.x * 256 + t;
    if (i < DD * DD) {
        uint32_t u = __float_as_uint(W[i]);
        Wb[i] = (uint16_t)((u + 0x7fffu + ((u >> 16) & 1u)) >> 16);
    }
}

// ---------- fused: gemm (blocks < GGRID) || bscat (blocks >= GGRID) ----------
// gemm: block = 64 rows x 128 cols, 4 waves, NO LDS. Wave wid: rows r0+wid*16..+16, all cols.
// h stored PERMUTED: position p = lr*8+q holds col (p&7)*16+(p>>3).
__global__ __launch_bounds__(256) void fused_k(const float* __restrict__ x,
                                               const uint16_t* __restrict__ Wb,
                                               const float* __restrict__ a,
                                               const int* __restrict__ src,
                                               const int* __restrict__ dst,
                                               uint16_t* __restrict__ hb,
                                               float* __restrict__ sArr,
                                               float* __restrict__ dArr,
                                               int* __restrict__ cntg,
                                               int* __restrict__ scnt,
                                               uint32_t* __restrict__ rec,
                                               uint2* __restrict__ spill) {
    __shared__ int lh[NBKT];
    __shared__ int gb[NBKT];
    const int t = threadIdx.x;

    if ((int)blockIdx.x < GGRID) {
        // ---------------- GEMM role ----------------
        const int l = t & 63, wid = t >> 6;
        const int r0 = blockIdx.x * GROWS;
        const int lr = l & 15, lk = l >> 4;

        f32x4 acc[8];
        #pragma unroll
        for (int c = 0; c < 8; ++c) acc[c] = f32x4{0.f, 0.f, 0.f, 0.f};

        const int arow = r0 + wid * 16 + lr;
        const int lrow = (arow < NN) ? arow : (NN - 1);        // clamp loads; guard stores
        const float* xp = x + (size_t)lrow * DD + lk * 8;

        #pragma unroll
        for (int kc = 0; kc < 4; ++kc) {
            float4 v0 = *(const float4*)(xp + kc * 32);
            float4 v1 = *(const float4*)(xp + kc * 32 + 4);
            union { uint32_t u[4]; short8 s; } A;
            A.u[0] = cvtpk(v0.x, v0.y); A.u[1] = cvtpk(v0.z, v0.w);
            A.u[2] = cvtpk(v1.x, v1.y); A.u[3] = cvtpk(v1.z, v1.w);
            #pragma unroll
            for (int c = 0; c < 8; ++c) {
                int col = c * 16 + lr;
                short8 bf_ = *(const short8*)(Wb + (size_t)col * DD + kc * 32 + lk * 8);
                acc[c] = __builtin_amdgcn_mfma_f32_16x16x32_bf16(A.s, bf_, acc[c], 0, 0, 0);
            }
        }

        // s/d projections (wave-local shuffle reduce over the 16 lr lanes)
        float avs[8], avd[8];
        #pragma unroll
        for (int c = 0; c < 8; ++c) {
            avs[c] = a[c * 16 + lr];
            avd[c] = a[DD + c * 16 + lr];
        }
        #pragma unroll
        for (int i = 0; i < 4; ++i) {
            float ps = 0.f, pd = 0.f;
            #pragma unroll
            for (int c = 0; c < 8; ++c) {
                ps = fmaf(acc[c][i], avs[c], ps);
                pd = fmaf(acc[c][i], avd[c], pd);
            }
            #pragma unroll
            for (int o = 8; o > 0; o >>= 1) {
                ps += __shfl_xor(ps, o);
                pd += __shfl_xor(pd, o);
            }
            int row = r0 + wid * 16 + lk * 4 + i;
            if (lr == 0 && row < NN) { sArr[row] = ps; dArr[row] = pd; }
        }

        // permuted h writeback: 4 x ushort8 per lane, no LDS
        #pragma unroll
        for (int i = 0; i < 4; ++i) {
            int row = r0 + wid * 16 + lk * 4 + i;
            if (row < NN) {
                union { uint32_t u[4]; ushort8 s; } H;
                H.u[0] = cvtpk(acc[0][i], acc[1][i]);
                H.u[1] = cvtpk(acc[2][i], acc[3][i]);
                H.u[2] = cvtpk(acc[4][i], acc[5][i]);
                H.u[3] = cvtpk(acc[6][i], acc[7][i]);
                *(ushort8*)(hb + (size_t)row * DD + lr * 8) = H.s;
            }
        }
    } else {
        // ---------------- BSCAT role ----------------
        int bb = blockIdx.x - GGRID;
        for (int k = t; k < NBKT; k += 256) lh[k] = 0;
        __syncthreads();
        int base = bb * BCH;
        unsigned pk[16]; int bk[16];
        #pragma unroll
        for (int i = 0; i < 16; ++i) {
            int idx = base + i * 256 + t;
            if (idx < NE) {
                int s_ = src[idx], d_ = dst[idx];
                bk[i] = d_ >> 5;
                pk[i] = ((unsigned)(d_ & 31) << 16) | (unsigned)s_;
                atomicAdd(&lh[bk[i]], 1);
            } else bk[i] = -1;
        }
        __syncthreads();
        for (int k = t; k < NBKT; k += 256) {
            int c = lh[k];
            lh[k] = 0;                       // becomes local cursor
            gb[k] = c ? atomicAdd(&cntg[k], c) : 0;
        }
        __syncthreads();
        #pragma unroll
        for (int i = 0; i < 16; ++i) {
            if (bk[i] >= 0) {
                int sl = atomicAdd(&lh[bk[i]], 1);
                int p = gb[bk[i]] + sl;
                if (p < CAP) {
                    rec[(size_t)bk[i] * CAP + p] = pk[i];
                } else {
                    int sp = atomicAdd(scnt, 1);
                    if (sp < SPILL_CAP)
                        spill[sp] = make_uint2(pk[i] & 0xffffu,
                                               (unsigned)(bk[i] * 32 + (int)(pk[i] >> 16)));
                }
            }
        }
    }
}

// ---------- agg: one 256-thread WG per 32-node bucket; LDS sort; r11-style gather ----------
__global__ __launch_bounds__(256) void bsort_agg_k(const uint16_t* __restrict__ hb,
                                                   const float* __restrict__ sA,
                                                   const float* __restrict__ dA,
                                                   const int* __restrict__ cntg,
                                                   const uint32_t* __restrict__ rec,
                                                   const int* __restrict__ scnt,
                                                   const uint2* __restrict__ spill,
                                                   float* __restrict__ out) {
    __shared__ uint32_t srt[CAP];   // 2.5 KB
    __shared__ float    eL[CAP];    // 2.5 KB
    __shared__ float dAl[32];
    __shared__ int h32[32];
    __shared__ int s33[33];
    __shared__ int curw[32];
    int t = threadIdx.x, l = t & 63, wid = t >> 6;
    int b = blockIdx.x;
    int cnt = cntg[b]; if (cnt > CAP) cnt = CAP;
    int beg = b * CAP;
    int n0 = b * 32;
    int ns = *scnt; if (ns > SPILL_CAP) ns = SPILL_CAP;
    if (t < 32) {
        h32[t] = 0;
        int n = n0 + t;
        dAl[t] = (n < NN) ? dA[n] : 0.f;
    }
    __syncthreads();

    // histogram + fused e-compute (records cached in registers; <=3 per thread)
    uint32_t rc[3]; float er[3]; int nrc = 0;
    for (int j = t; j < cnt; j += 256) {
        uint32_t r = rec[beg + j];
        rc[nrc] = r;
        atomicAdd(&h32[r >> 16], 1);
        float z = sA[r & 0xffffu] + dAl[r >> 16];
        er[nrc] = 1.f / (1.f + __expf(-z));
        ++nrc;
    }
    __syncthreads();
    if (wid == 0) {
        int v = (l < 32) ? h32[l] : 0;
        int inc = v;
        #pragma unroll
        for (int o = 1; o < 32; o <<= 1) {
            int nb = __shfl_up(inc, o);
            if (l >= o) inc += nb;
        }
        if (l < 32) { s33[l + 1] = inc; curw[l] = inc - v; }
        if (l == 0) s33[0] = 0;
    }
    __syncthreads();
    for (int k = 0; k < nrc; ++k) {
        uint32_t r = rc[k];
        int p = atomicAdd(&curw[r >> 16], 1);
        srt[p] = r;
        eL[p] = er[k];
    }
    __syncthreads();

    // gather (r11 form): 8 records/iter, 2 independent uint4 loads per wave.
    // quarter q handles records j+q, j+4+q; lane sl reads uint4 (8 bf16) at byte sl*16.
    // permuted layout: position 8*sl+k <-> col k*16+sl  =>  acc[k] is col k*16+sl.
    const int q = l >> 4, sl = l & 15;
    const char* hbp = (const char*)hb;
    #pragma unroll 1
    for (int rr = 0; rr < 8; ++rr) {
        int d = wid * 8 + rr;
        int n = n0 + d;
        if (n >= NN) break;
        int js = s33[d], je = s33[d + 1];
        float acc[8] = {0.f,0.f,0.f,0.f,0.f,0.f,0.f,0.f};
        for (int j = js; j < je; j += 8) {
            int j0 = j + q, j1 = j + 4 + q;
            bool v0 = j0 < je, v1 = j1 < je;
            uint32_t r0 = srt[v0 ? j0 : js];
            uint32_t r1 = srt[v1 ? j1 : js];
            float e0 = v0 ? eL[j0] : 0.f;
            float e1 = v1 ? eL[j1] : 0.f;
            uint4 u0 = *(const uint4*)(hbp + (size_t)(r0 & 0xffffu) * 256 + sl * 16);
            uint4 u1 = *(const uint4*)(hbp + (size_t)(r1 & 0xffffu) * 256 + sl * 16);
            acc[0] = fmaf(e0, bf_lo(u0.x), acc[0]); acc[1] = fmaf(e0, bf_hi(u0.x), acc[1]);
            acc[2] = fmaf(e0, bf_lo(u0.y), acc[2]); acc[3] = fmaf(e0, bf_hi(u0.y), acc[3]);
            acc[4] = fmaf(e0, bf_lo(u0.z), acc[4]); acc[5] = fmaf(e0, bf_hi(u0.z), acc[5]);
            acc[6] = fmaf(e0, bf_lo(u0.w), acc[6]); acc[7] = fmaf(e0, bf_hi(u0.w), acc[7]);
            acc[0] = fmaf(e1, bf_lo(u1.x), acc[0]); acc[1] = fmaf(e1, bf_hi(u1.x), acc[1]);
            acc[2] = fmaf(e1, bf_lo(u1.y), acc[2]); acc[3] = fmaf(e1, bf_hi(u1.y), acc[3]);
            acc[4] = fmaf(e1, bf_lo(u1.z), acc[4]); acc[5] = fmaf(e1, bf_hi(u1.z), acc[5]);
            acc[6] = fmaf(e1, bf_lo(u1.w), acc[6]); acc[7] = fmaf(e1, bf_hi(u1.w), acc[7]);
        }
        // fold the 4 record-parity partials (quarters) into all lanes
        #pragma unroll
        for (int k = 0; k < 8; ++k) {
            acc[k] += __shfl_xor(acc[k], 16);
            acc[k] += __shfl_xor(acc[k], 32);
        }
        // inline spill drain (statistically empty); post-combine, no double count
        if (ns > 0) {
            for (int i = 0; i < ns; ++i) {
                uint2 sp = spill[i];
                if ((int)sp.y == n) {
                    float z = sA[sp.x] + dAl[d];
                    float e = 1.f / (1.f + __expf(-z));
                    uint4 u = *(const uint4*)(hbp + (size_t)sp.x * 256 + sl * 16);
                    acc[0] = fmaf(e, bf_lo(u.x), acc[0]); acc[1] = fmaf(e, bf_hi(u.x), acc[1]);
                    acc[2] = fmaf(e, bf_lo(u.y), acc[2]); acc[3] = fmaf(e, bf_hi(u.y), acc[3]);
                    acc[4] = fmaf(e, bf_lo(u.z), acc[4]); acc[5] = fmaf(e, bf_hi(u.z), acc[5]);
                    acc[6] = fmaf(e, bf_lo(u.w), acc[6]); acc[7] = fmaf(e, bf_hi(u.w), acc[7]);
                }
            }
        }
        // store: lane (q,sl) writes cols (2q)*16+sl and (2q+1)*16+sl (compile-time selects)
        float vx = (q == 0) ? acc[0] : (q == 1) ? acc[2] : (q == 2) ? acc[4] : acc[6];
        float vy = (q == 0) ? acc[1] : (q == 1) ? acc[3] : (q == 2) ? acc[5] : acc[7];
        float* orow = out + (size_t)n * DD;
        orow[(2 * q) * 16 + sl]     = vx;
        orow[(2 * q + 1) * 16 + sl] = vy;
    }
}

// ---------- fallback: direct atomic scatter-add (permuted hb layout) ----------
__global__ __launch_bounds__(256) void edge_atomic_k(const int* __restrict__ src, const int* __restrict__ dst,
                                                     const float* __restrict__ sArr, const float* __restrict__ dArr,
                                                     const uint32_t* __restrict__ hb, float* __restrict__ out) {
    int wid = threadIdx.x >> 6, l = threadIdx.x & 63;
    int e = blockIdx.x * 4 + wid;
    if (e >= NE) return;
    int sv = src[e], dv = dst[e];
    float z = sArr[sv] + dArr[dv];
    float ev = 1.0f / (1.0f + __expf(-z));
    uint32_t u = hb[(size_t)sv * 64 + l];
    int colx = 32 * (l & 3) + (l >> 2);
    atomicAdd(&out[(size_t)dv * DD + colx],      ev * bf_lo(u));
    atomicAdd(&out[(size_t)dv * DD + colx + 16], ev * bf_hi(u));
}

extern "C" void kernel_launch(void* const* d_in, const int* in_sizes, int n_in,
                              void* d_out, int out_size, void* d_ws, size_t ws_size,
                              hipStream_t stream) {
    const float* x  = (const float*)d_in[0];
    const float* W  = (const float*)d_in[1];
    const float* a  = (const float*)d_in[2];
    const int* src  = (const int*)d_in[3];
    const int* dst  = (const int*)d_in[4];
    float* out = (float*)d_out;

    char* p = (char*)d_ws;
    uint16_t* hb = (uint16_t*)p;            p += (size_t)NN * DD * 2;       // 12.8 MB
    uint16_t* Wb = (uint16_t*)p;            p += (size_t)DD * DD * 2;       // 32 KB
    float* sA    = (float*)p;               p += (size_t)NN * 4;
    float* dA    = (float*)p;               p += (size_t)NN * 4;
    int*   cntg  = (int*)p;                 p += (size_t)NBKT * 4;
    int*   scnt  = (int*)p;                 p += 16;
    uint32_t* rec = (uint32_t*)(((uintptr_t)p + 15) & ~(uintptr_t)15);
    p = (char*)(rec + (size_t)NBKT * CAP);                                   // 4.0 MB
    uint2* spill = (uint2*)p;               p += (size_t)SPILL_CAP * 8;      // 0.25 MB
    size_t need  = (size_t)(p - (char*)d_ws);

    if (ws_size >= need) {
        prep_k<<<64, 256, 0, stream>>>(W, Wb, cntg);                 // zeros cntg+scnt
        fused_k<<<GGRID + BGRID, 256, 0, stream>>>(x, Wb, a, src, dst,
                                                   hb, sA, dA, cntg, scnt, rec, spill);
        bsort_agg_k<<<NBKT, 256, 0, stream>>>(hb, sA, dA, cntg, rec, scnt, spill, out);
    } else {
        hipMemsetAsync(out, 0, sizeof(float) * (size_t)NN * DD, stream);
        prep_k<<<64, 256, 0, stream>>>(W, Wb, cntg);
        fused_k<<<GGRID, 256, 0, stream>>>(x, Wb, a, src, dst,
                                           hb, sA, dA, cntg, scnt, rec, spill);
        edge_atomic_k<<<NE / 4, 256, 0, stream>>>(src, dst, sA, dA, (const uint32_t*)hb, out);
    }
}